// Round 3
// baseline (7585.100 us; speedup 1.0000x reference)
//
#include <hip/hip_runtime.h>
#include <hip/hip_bf16.h>
#include <hip/hip_cooperative_groups.h>
#include <math.h>

namespace cg = cooperative_groups;

#define B_ 64
#define S_ 512
#define I_ 256
#define H_ 1024
#define O_ 256

#define OUT_OFF (B_*O_)      // 16384 floats: final output
#define SLOT    (B_*H_)      // 65536 floats per hidden timestep slot

typedef __attribute__((ext_vector_type(8))) short bf16x8;  // 8 bf16 = 4 VGPRs
typedef __attribute__((ext_vector_type(4))) float f32x4;

#define LDSK 1032            // padded row stride (1024 + 8 bf16): balanced 32-bank access

// ---------------- zero hidden slot 0 (h0 = 0) + hbf0 ----------------
__global__ void k_zero(float* __restrict__ hid, float* __restrict__ hbf0) {
    int i = blockIdx.x * 256 + threadIdx.x;          // 64 blocks * 256 = 16384 float4
    ((float4*)hid)[i] = make_float4(0.f, 0.f, 0.f, 0.f);
    if (i < B_ * H_ * 2 / 16)                        // bf16 h ping-pong buffers zeroed
        ((float4*)hbf0)[i] = make_float4(0.f, 0.f, 0.f, 0.f);
}

// ---------------- convert whh fp32 -> bf16 (natural row-major layout) ----------------
__global__ void k_cvt(const float* __restrict__ src, unsigned short* __restrict__ dst) {
    int i = blockIdx.x * 256 + threadIdx.x;
    float4 v = ((const float4*)src)[i];
    ushort4 o;
    o.x = __builtin_bit_cast(unsigned short, __float2bfloat16(v.x));
    o.y = __builtin_bit_cast(unsigned short, __float2bfloat16(v.y));
    o.z = __builtin_bit_cast(unsigned short, __float2bfloat16(v.z));
    o.w = __builtin_bit_cast(unsigned short, __float2bfloat16(v.w));
    ((ushort4*)dst)[i] = o;
}

// ---------------- generic transpose src[R][C] -> dst[C][R] ----------------
__global__ void k_transpose(const float* __restrict__ src, float* __restrict__ dst,
                            int R, int C) {
    __shared__ float tile[32][33];
    int c0 = blockIdx.x * 32, r0 = blockIdx.y * 32;
    int tx = threadIdx.x, ty = threadIdx.y;          // block (32,8)
#pragma unroll
    for (int j = 0; j < 32; j += 8)
        tile[ty + j][tx] = src[(size_t)(r0 + ty + j) * C + c0 + tx];
    __syncthreads();
#pragma unroll
    for (int j = 0; j < 32; j += 8)
        dst[(size_t)(c0 + ty + j) * R + r0 + tx] = tile[tx][ty + j];
}

// ---------------- x_proj: hid[t+1][b][h] = bias[h] + sum_i x[b][t][i] * W_ih[h][i] ----------------
__global__ __launch_bounds__(256) void k_xproj(const float* __restrict__ x,
                                               const float* __restrict__ wihT, // [I_][H_]
                                               const float* __restrict__ bias,
                                               float* __restrict__ hid) {
    const int t   = blockIdx.x;
    const int hq0 = blockIdx.y * 16;                 // h-quad base (64 h per tile)
    __shared__ float xs[B_][260];                    // +4 pad
    const int tid = threadIdx.x;

#pragma unroll
    for (int it = 0; it < 16; ++it) {
        int f4 = it * 256 + tid;
        int b = f4 >> 6, iq = f4 & 63;
        float4 v = ((const float4*)x)[(size_t)b * (S_ * I_ / 4) + t * (I_ / 4) + iq];
        *(float4*)&xs[b][iq * 4] = v;
    }
    __syncthreads();

    const int hq = tid & 15;
    const int b0 = (tid >> 4) * 4;
    float4 acc[4];
    float4 bs = ((const float4*)bias)[hq0 + hq];
#pragma unroll
    for (int i = 0; i < 4; ++i) acc[i] = bs;

    const float4* w4p = (const float4*)wihT;
#pragma unroll 4
    for (int k = 0; k < I_; ++k) {
        float4 w = w4p[(size_t)k * (H_ / 4) + hq0 + hq];
#pragma unroll
        for (int i = 0; i < 4; ++i) {
            float xv = xs[b0 + i][k];
            acc[i].x += xv * w.x; acc[i].y += xv * w.y;
            acc[i].z += xv * w.z; acc[i].w += xv * w.w;
        }
    }

    float4* out4 = (float4*)hid;
#pragma unroll
    for (int i = 0; i < 4; ++i)
        out4[(size_t)(t + 1) * (SLOT / 4) + (b0 + i) * (H_ / 4) + hq0 + hq] = acc[i];
}

// ---------------- persistent recurrence: all 512 steps, one launch ----------------
// 64 WGs x 256 thr (cooperative). WG = 16-row W slice resident in LDS for the
// whole sequence. Per step, wave w computes D[16r x 16b] via 32 chained
// bf16 MFMAs; one grid.sync() per step orders h ping-pong across XCDs.
__global__ __launch_bounds__(256) void k_loop(
    const unsigned short* __restrict__ whhbf,   // [H_][H_] bf16 natural
    unsigned short* __restrict__ hbuf0,         // [B_][H_] bf16 ping
    unsigned short* __restrict__ hbuf1,         // [B_][H_] bf16 pong
    float* __restrict__ hid)
{
    const int slice = blockIdx.x;
    __shared__ unsigned short Ws[16 * LDSK];
    const int tid = threadIdx.x;

    // stage 16 W rows (contiguous 32 KB) -> padded LDS, ONCE for all 512 steps
    {
        const float4* src = (const float4*)(whhbf + (size_t)slice * 16 * H_);
#pragma unroll
        for (int it = 0; it < 8; ++it) {
            int c = it * 256 + tid;                  // 2048 chunks of 16B (8 bf16)
            float4 v = src[c];
            int row = c >> 7, off = (c & 127) * 8;
            *(float4*)&Ws[row * LDSK + off] = v;
        }
    }
    __syncthreads();

    const int w    = tid >> 6;                       // wave = b-tile
    const int lane = tid & 63;
    const int n    = lane & 15;                      // A-row (r_local) AND B-col (b_local)
    const int quad = lane >> 4;
    const int b    = w * 16 + n;

    const unsigned short* ap = &Ws[n * LDSK + quad * 8];
    const int r0 = slice * 16 + quad * 4;            // C/D: row = quad*4+reg, col = n
    const size_t didx = (size_t)b * (H_ / 4) + (r0 >> 2);
    const size_t hoff = (size_t)b * H_;

    cg::grid_group grid = cg::this_grid();

    for (int t = 0; t < S_; ++t) {
        const unsigned short* hp = (t & 1) ? hbuf1 : hbuf0;
        unsigned short*       hn = (t & 1) ? hbuf0 : hbuf1;
        float4* slot1 = (float4*)(hid + (size_t)(t + 1) * SLOT);

        float4 xp = slot1[didx];                     // x_proj + bias (prefetch early)
        const unsigned short* bp = hp + hoff + quad * 8;

        f32x4 acc = {0.f, 0.f, 0.f, 0.f};
#pragma unroll
        for (int kk = 0; kk < 32; ++kk) {
            bf16x8 af = *(const bf16x8*)(ap + kk * 32);
            bf16x8 bf = *(const bf16x8*)(bp + kk * 32);
            acc = __builtin_amdgcn_mfma_f32_16x16x32_bf16(af, bf, acc, 0, 0, 0);
        }

        float4 hv;
        hv.x = tanhf(acc[0] + xp.x);
        hv.y = tanhf(acc[1] + xp.y);
        hv.z = tanhf(acc[2] + xp.z);
        hv.w = tanhf(acc[3] + xp.w);
        slot1[didx] = hv;

        ushort4 hb;
        hb.x = __builtin_bit_cast(unsigned short, __float2bfloat16(hv.x));
        hb.y = __builtin_bit_cast(unsigned short, __float2bfloat16(hv.y));
        hb.z = __builtin_bit_cast(unsigned short, __float2bfloat16(hv.z));
        hb.w = __builtin_bit_cast(unsigned short, __float2bfloat16(hv.w));
        *(ushort4*)(hn + hoff + r0) = hb;

        grid.sync();                                 // device-scope fence + barrier
    }
}

// ---------------- final fc ----------------
__global__ __launch_bounds__(256) void k_fc(const float* __restrict__ fcwT,  // [H_][O_]
                                            const float* __restrict__ fcb,
                                            const float* __restrict__ hid,
                                            float* __restrict__ outp) {
    const int b = blockIdx.x;
    __shared__ float hl[H_];
    const int tid = threadIdx.x;
    ((float4*)hl)[tid] = ((const float4*)(hid + (size_t)S_ * SLOT + b * H_))[tid];
    __syncthreads();
    float acc = fcb[tid];
#pragma unroll 4
    for (int k = 0; k < H_; ++k)
        acc += fcwT[(size_t)k * O_ + tid] * hl[k];
    outp[b * O_ + tid] = acc;
}

extern "C" void kernel_launch(void* const* d_in, const int* in_sizes, int n_in,
                              void* d_out, int out_size, void* d_ws, size_t ws_size,
                              hipStream_t stream) {
    const float* x    = (const float*)d_in[0];
    const float* wih  = (const float*)d_in[1];
    const float* whh  = (const float*)d_in[2];
    const float* bias = (const float*)d_in[3];
    const float* fcw  = (const float*)d_in[4];
    const float* fcb  = (const float*)d_in[5];

    float* outp = (float*)d_out;
    float* hid  = outp + OUT_OFF;

    // ws layout: whhbf 2MB | hbf0 128KB | hbf1 128KB | wihT 1MB | fcwT 1MB  (≈4.3MB)
    unsigned short* whhbf = (unsigned short*)d_ws;
    unsigned short* hbf0  = whhbf + (size_t)H_ * H_;
    unsigned short* hbf1  = hbf0 + (size_t)B_ * H_;
    float* wihT = (float*)(hbf1 + (size_t)B_ * H_);
    float* fcwT = wihT + (size_t)I_ * H_;

    k_zero<<<SLOT / 4 / 256, 256, 0, stream>>>(hid, (float*)hbf0);
    k_cvt<<<H_ * H_ / 4 / 256, 256, 0, stream>>>(whh, whhbf);
    k_transpose<<<dim3(I_ / 32, H_ / 32), dim3(32, 8), 0, stream>>>(wih, wihT, H_, I_);
    k_transpose<<<dim3(H_ / 32, O_ / 32), dim3(32, 8), 0, stream>>>(fcw, fcwT, O_, H_);

    k_xproj<<<dim3(S_, H_ / 64), 256, 0, stream>>>(x, wihT, bias, hid);

    {
        void* args[] = {(void*)&whhbf, (void*)&hbf0, (void*)&hbf1, (void*)&hid};
        hipLaunchCooperativeKernel((void*)k_loop, dim3(64), dim3(256), args, 0, stream);
    }

    k_fc<<<B_, 256, 0, stream>>>(fcwT, fcb, hid, outp);
}

// Round 4
// 5219.204 us; speedup vs baseline: 1.4533x; 1.4533x over previous
//
#include <hip/hip_runtime.h>
#include <hip/hip_bf16.h>
#include <hip/hip_cooperative_groups.h>
#include <math.h>

#define B_ 64
#define S_ 512
#define I_ 256
#define H_ 1024
#define O_ 256

#define OUT_OFF (B_*O_)      // 16384 floats: final output
#define SLOT    (B_*H_)      // 65536 floats per hidden timestep slot
#define SLOTBF  (B_*H_)      // bf16 h buffer elements

typedef __attribute__((ext_vector_type(8))) short bf16x8;  // 8 bf16 = 4 VGPRs
typedef __attribute__((ext_vector_type(4))) float f32x4;

#define AT_LD(p)    __hip_atomic_load((p), __ATOMIC_RELAXED, __HIP_MEMORY_SCOPE_AGENT)
#define AT_ST(p, v) __hip_atomic_store((p), (v), __ATOMIC_RELAXED, __HIP_MEMORY_SCOPE_AGENT)

// ---------------- prep: zero hid slot0 (cached), h ping-pong + cnt (COHERENT path) ----------------
// h/cnt are consumed via L2-bypassing (sc1) loads in k_loop, so their zeros must
// reach the memory-side L3 — a cached zero could strand in one XCD's L2.
__global__ void k_zero(float* __restrict__ hid, unsigned long long* __restrict__ hbf,
                       int* __restrict__ cnt) {
    int i = blockIdx.x * 256 + threadIdx.x;          // 64 blocks * 256 = 16384
    ((float4*)hid)[i] = make_float4(0.f, 0.f, 0.f, 0.f);
    AT_ST(&hbf[i], 0ull);                            // hbf0 (first 16384 u64 = 128 KB)
    AT_ST(&hbf[i + 16384], 0ull);                    // hbf1
    if (i < S_) AT_ST(&cnt[i], 0);
}

// ---------------- convert whh fp32 -> bf16 (natural row-major layout) ----------------
__global__ void k_cvt(const float* __restrict__ src, unsigned short* __restrict__ dst) {
    int i = blockIdx.x * 256 + threadIdx.x;
    float4 v = ((const float4*)src)[i];
    ushort4 o;
    o.x = __builtin_bit_cast(unsigned short, __float2bfloat16(v.x));
    o.y = __builtin_bit_cast(unsigned short, __float2bfloat16(v.y));
    o.z = __builtin_bit_cast(unsigned short, __float2bfloat16(v.z));
    o.w = __builtin_bit_cast(unsigned short, __float2bfloat16(v.w));
    ((ushort4*)dst)[i] = o;
}

// ---------------- generic transpose src[R][C] -> dst[C][R] ----------------
__global__ void k_transpose(const float* __restrict__ src, float* __restrict__ dst,
                            int R, int C) {
    __shared__ float tile[32][33];
    int c0 = blockIdx.x * 32, r0 = blockIdx.y * 32;
    int tx = threadIdx.x, ty = threadIdx.y;          // block (32,8)
#pragma unroll
    for (int j = 0; j < 32; j += 8)
        tile[ty + j][tx] = src[(size_t)(r0 + ty + j) * C + c0 + tx];
    __syncthreads();
#pragma unroll
    for (int j = 0; j < 32; j += 8)
        dst[(size_t)(c0 + ty + j) * R + r0 + tx] = tile[tx][ty + j];
}

// ---------------- x_proj: hid[t+1][b][h] = bias[h] + sum_i x[b][t][i] * W_ih[h][i] ----------------
__global__ __launch_bounds__(256) void k_xproj(const float* __restrict__ x,
                                               const float* __restrict__ wihT, // [I_][H_]
                                               const float* __restrict__ bias,
                                               float* __restrict__ hid) {
    const int t   = blockIdx.x;
    const int hq0 = blockIdx.y * 16;                 // h-quad base (64 h per tile)
    __shared__ float xs[B_][260];                    // +4 pad
    const int tid = threadIdx.x;

#pragma unroll
    for (int it = 0; it < 16; ++it) {
        int f4 = it * 256 + tid;
        int b = f4 >> 6, iq = f4 & 63;
        float4 v = ((const float4*)x)[(size_t)b * (S_ * I_ / 4) + t * (I_ / 4) + iq];
        *(float4*)&xs[b][iq * 4] = v;
    }
    __syncthreads();

    const int hq = tid & 15;
    const int b0 = (tid >> 4) * 4;
    float4 acc[4];
    float4 bs = ((const float4*)bias)[hq0 + hq];
#pragma unroll
    for (int i = 0; i < 4; ++i) acc[i] = bs;

    const float4* w4p = (const float4*)wihT;
#pragma unroll 4
    for (int k = 0; k < I_; ++k) {
        float4 w = w4p[(size_t)k * (H_ / 4) + hq0 + hq];
#pragma unroll
        for (int i = 0; i < 4; ++i) {
            float xv = xs[b0 + i][k];
            acc[i].x += xv * w.x; acc[i].y += xv * w.y;
            acc[i].z += xv * w.z; acc[i].w += xv * w.w;
        }
    }

    float4* out4 = (float4*)hid;
#pragma unroll
    for (int i = 0; i < 4; ++i)
        out4[(size_t)(t + 1) * (SLOT / 4) + (b0 + i) * (H_ / 4) + hq0 + hq] = acc[i];
}

// ---------------- persistent recurrence, hand-rolled barrier ----------------
// 64 WGs x 256 thr (cooperative, co-resident). WG = 16-row W slice held in
// VGPRs (A-frags are step-invariant: 32 x bf16x8 = 128 VGPRs). Per step:
// spin on cnt[t-1], read h_t via agent-scope (L2-bypass) loads, 32 MFMAs in
// 4 independent chains, tanh, agent-scope h_{t+1} store, arrive on cnt[t].
// No fences, no L2 maintenance: all cross-WG data lives at the L3 coherence
// point. fp32 hid write + next xp prefetch hide under the barrier.
__global__ __launch_bounds__(256) void k_loop(
    const unsigned short* __restrict__ whhbf,   // [H_][H_] bf16 natural
    unsigned short* __restrict__ hbuf0,         // [B_][H_] bf16 ping
    unsigned short* __restrict__ hbuf1,         // [B_][H_] bf16 pong
    float* __restrict__ hid,
    int* __restrict__ cnt)
{
    const int slice = blockIdx.x;
    const int tid  = threadIdx.x;
    const int w    = tid >> 6;                       // wave = b-tile
    const int lane = tid & 63;
    const int n    = lane & 15;                      // A-row (r_local) AND B-col (b_local)
    const int quad = lane >> 4;
    const int b    = w * 16 + n;

    // ---- preload A fragments (W rows) into VGPRs, once ----
    bf16x8 af[32];
    {
        const unsigned short* ag = whhbf + (size_t)(slice * 16 + n) * H_ + quad * 8;
#pragma unroll
        for (int kk = 0; kk < 32; ++kk)
            af[kk] = *(const bf16x8*)(ag + kk * 32);
    }

    const int r0 = slice * 16 + quad * 4;            // C/D: row = quad*4+reg, col = n
    const size_t didx = (size_t)b * (H_ / 4) + (r0 >> 2);
    const size_t hoff = (size_t)b * H_;

    float4 xp = ((float4*)(hid + (size_t)1 * SLOT))[didx];   // x_proj+bias for t=0

    for (int t = 0; t < S_; ++t) {
        const unsigned short* hp = (t & 1) ? hbuf1 : hbuf0;
        unsigned short*       hn = (t & 1) ? hbuf0 : hbuf1;

        if (t > 0) {                                 // wait for all h_t producers
            if (tid == 0)
                while (AT_LD(&cnt[t - 1]) < 64) {}
            __syncthreads();
        }

        // B fragments: h_t via coherent 8B loads (L3), 64 independent loads
        const unsigned long long* bp =
            (const unsigned long long*)(hp + hoff + quad * 8);
        f32x4 a0 = {0.f,0.f,0.f,0.f}, a1 = a0, a2 = a0, a3 = a0;
#pragma unroll
        for (int kk = 0; kk < 32; kk += 4) {
#pragma unroll
            for (int j = 0; j < 4; ++j) {
                ulonglong2 raw;
                raw.x = AT_LD(bp + (kk + j) * 8);    // stride 32 shorts = 8 u64
                raw.y = AT_LD(bp + (kk + j) * 8 + 1);
                bf16x8 bf = __builtin_bit_cast(bf16x8, raw);
                if (j == 0)      a0 = __builtin_amdgcn_mfma_f32_16x16x32_bf16(af[kk+j], bf, a0, 0, 0, 0);
                else if (j == 1) a1 = __builtin_amdgcn_mfma_f32_16x16x32_bf16(af[kk+j], bf, a1, 0, 0, 0);
                else if (j == 2) a2 = __builtin_amdgcn_mfma_f32_16x16x32_bf16(af[kk+j], bf, a2, 0, 0, 0);
                else             a3 = __builtin_amdgcn_mfma_f32_16x16x32_bf16(af[kk+j], bf, a3, 0, 0, 0);
            }
        }
        f32x4 acc;
#pragma unroll
        for (int i = 0; i < 4; ++i) acc[i] = (a0[i] + a1[i]) + (a2[i] + a3[i]);

        float4 hv;
        hv.x = tanhf(acc[0] + xp.x);
        hv.y = tanhf(acc[1] + xp.y);
        hv.z = tanhf(acc[2] + xp.z);
        hv.w = tanhf(acc[3] + xp.w);

        ushort4 hb;
        hb.x = __builtin_bit_cast(unsigned short, __float2bfloat16(hv.x));
        hb.y = __builtin_bit_cast(unsigned short, __float2bfloat16(hv.y));
        hb.z = __builtin_bit_cast(unsigned short, __float2bfloat16(hv.z));
        hb.w = __builtin_bit_cast(unsigned short, __float2bfloat16(hv.w));
        AT_ST((unsigned long long*)(hn + hoff + r0),
              __builtin_bit_cast(unsigned long long, hb));

        __syncthreads();                             // drains vmcnt: h stores complete
        if (tid == 0)
            __hip_atomic_fetch_add(&cnt[t], 1, __ATOMIC_RELAXED, __HIP_MEMORY_SCOPE_AGENT);

        // under the barrier: fp32 hidden_states write + next xp prefetch (private)
        ((float4*)(hid + (size_t)(t + 1) * SLOT))[didx] = hv;
        if (t + 1 < S_)
            xp = ((float4*)(hid + (size_t)(t + 2) * SLOT))[didx];
    }
}

// ---------------- final fc ----------------
__global__ __launch_bounds__(256) void k_fc(const float* __restrict__ fcwT,  // [H_][O_]
                                            const float* __restrict__ fcb,
                                            const float* __restrict__ hid,
                                            float* __restrict__ outp) {
    const int b = blockIdx.x;
    __shared__ float hl[H_];
    const int tid = threadIdx.x;
    ((float4*)hl)[tid] = ((const float4*)(hid + (size_t)S_ * SLOT + b * H_))[tid];
    __syncthreads();
    float acc = fcb[tid];
#pragma unroll 4
    for (int k = 0; k < H_; ++k)
        acc += fcwT[(size_t)k * O_ + tid] * hl[k];
    outp[b * O_ + tid] = acc;
}

extern "C" void kernel_launch(void* const* d_in, const int* in_sizes, int n_in,
                              void* d_out, int out_size, void* d_ws, size_t ws_size,
                              hipStream_t stream) {
    const float* x    = (const float*)d_in[0];
    const float* wih  = (const float*)d_in[1];
    const float* whh  = (const float*)d_in[2];
    const float* bias = (const float*)d_in[3];
    const float* fcw  = (const float*)d_in[4];
    const float* fcb  = (const float*)d_in[5];

    float* outp = (float*)d_out;
    float* hid  = outp + OUT_OFF;

    // ws: whhbf 2MB | hbf0 128KB | hbf1 128KB | wihT 1MB | fcwT 1MB | cnt 2KB
    unsigned short* whhbf = (unsigned short*)d_ws;
    unsigned short* hbf0  = whhbf + (size_t)H_ * H_;
    unsigned short* hbf1  = hbf0 + (size_t)SLOTBF;
    float* wihT = (float*)(hbf1 + (size_t)SLOTBF);
    float* fcwT = wihT + (size_t)I_ * H_;
    int*   cnt  = (int*)(fcwT + (size_t)H_ * O_);

    k_zero<<<SLOT / 4 / 256, 256, 0, stream>>>(hid, (unsigned long long*)hbf0, cnt);
    k_cvt<<<H_ * H_ / 4 / 256, 256, 0, stream>>>(whh, whhbf);
    k_transpose<<<dim3(I_ / 32, H_ / 32), dim3(32, 8), 0, stream>>>(wih, wihT, H_, I_);
    k_transpose<<<dim3(H_ / 32, O_ / 32), dim3(32, 8), 0, stream>>>(fcw, fcwT, O_, H_);

    k_xproj<<<dim3(S_, H_ / 64), 256, 0, stream>>>(x, wihT, bias, hid);

    {
        void* args[] = {(void*)&whhbf, (void*)&hbf0, (void*)&hbf1, (void*)&hid, (void*)&cnt};
        hipLaunchCooperativeKernel((void*)k_loop, dim3(64), dim3(256), args, 0, stream);
    }

    k_fc<<<B_, 256, 0, stream>>>(fcwT, fcb, hid, outp);
}